// Round 15
// baseline (378.421 us; speedup 1.0000x reference)
//
#include <hip/hip_runtime.h>

#define SQ   2048
#define DIMD 2048
#define NH   16
#define HD   128
#define MR   4096   // B*S
#define QBLK 128
#define KBLK 32

using u16 = unsigned short;
using u32 = unsigned int;
using s16x8 = __attribute__((ext_vector_type(8))) short;
using u16x8 = __attribute__((ext_vector_type(8))) unsigned short;
using f32x4 = __attribute__((ext_vector_type(4))) float;
using as3u  = __attribute__((address_space(3))) u32;
using as1u  = __attribute__((address_space(1))) u32;

__device__ __forceinline__ u16 f2bf(float f) {
  u32 x = __float_as_uint(f);
  return (u16)((x + 0x7fffu + ((x >> 16) & 1u)) >> 16);
}
__device__ __forceinline__ float bf2f(u16 u) {
  return __uint_as_float(((u32)u) << 16);
}
__device__ __forceinline__ void gld16(const void* g, void* l) {
  __builtin_amdgcn_global_load_lds((as1u*)g, (as3u*)l, 16, 0, 0);
}
#define MFMA16 __builtin_amdgcn_mfma_f32_16x16x32_bf16

// ---------------- fp32 -> bf16 convert: x + 4 weights, ONE launch -----------
__global__ __launch_bounds__(256) void cvt_all(
    const float* __restrict__ x,
    const float* __restrict__ w0, const float* __restrict__ w1,
    const float* __restrict__ w2, const float* __restrict__ w3,
    u16* __restrict__ xb, u16* __restrict__ wb) {
  int y = blockIdx.y;
  const float* s;
  u16* dst;
  int n4;
  if (y == 4) { s = x; dst = xb; n4 = MR * DIMD / 4; }
  else {
    s = (y == 0) ? w0 : (y == 1) ? w1 : (y == 2) ? w2 : w3;
    dst = wb + (size_t)y * DIMD * DIMD;
    n4 = DIMD * DIMD / 4;
  }
  int i = blockIdx.x * 256 + threadIdx.x;
  int st = gridDim.x * 256;
  for (; i < n4; i += st) {
    float4 v = ((const float4*)s)[i];
    u32 lo = (u32)f2bf(v.x) | ((u32)f2bf(v.y) << 16);
    u32 hi = (u32)f2bf(v.z) | ((u32)f2bf(v.w) << 16);
    ((uint2*)dst)[i] = make_uint2(lo, hi);
  }
}

// ---------------- RoPE (1 wave = 1 row of 128) ----------------
__global__ __launch_bounds__(256) void rope_kernel(
    const u16* __restrict__ Qin, const u16* __restrict__ Kin,
    u16* __restrict__ Qout, u16* __restrict__ Kout,
    const float* __restrict__ cosT, const float* __restrict__ sinT) {
  int ten = blockIdx.y;
  const u16* in = ten ? Kin : Qin;
  u16* outp     = ten ? Kout : Qout;
  float scl     = ten ? 1.0f : 0.08838834764831845f;  // fold 1/sqrt(DH) into Q
  int row = blockIdx.x * 4 + (threadIdx.x >> 6);
  int j   = threadIdx.x & 63;
  int s   = row & (SQ - 1);
  const u16* r = in + (size_t)row * HD;
  u16* w = outp + (size_t)row * HD;
  float c  = cosT[s * HD + j];
  float si = sinT[s * HD + j];
  float a  = bf2f(r[j]);
  float b  = bf2f(r[j + 64]);
  float ev = bf2f(r[2 * j]);
  float od = bf2f(r[2 * j + 1]);
  w[j]      = f2bf((a * c - od * si) * scl);
  w[j + 64] = f2bf((b * c + ev * si) * scl);
}

// ---------------- GEMM C = A(M,K) * W(N,K)^T  (m97 structure) ---------------
// 2D-chunked XCD swizzle: xcd = bid&7 owns an 8mi x 8ni square (A-panels 4MB
// + W-panels 4MB in its L2, 8x reuse per fetch; A shared across the 3 y's).
// Was: every XCD fetched all of W per y (FETCH 192MB = 8 XCD x 8MB x 3y).
// MODE 0: QKV dim3(512,3); y=0,1 scatter (b,h,s,dh); y=2 (V) rotation-
//         addressed 32KB-alias transpose -> Vt (b,h,dh,s).
// MODE 1: O-proj -> fp32 row-major.
template <int MODE>
__global__ __launch_bounds__(256, 5) void gemm_bt(
    const u16* __restrict__ A,
    const u16* __restrict__ W0, const u16* __restrict__ W1, const u16* __restrict__ W2,
    u16* __restrict__ O0, u16* __restrict__ O1, u16* __restrict__ O2,
    float* __restrict__ Ofp) {
  __shared__ alignas(16) u16 SM[16384];   // 32 KB: staging; aliased by V-epi
  u16* lA = SM;          // [2][4096]
  u16* lB = SM + 8192;   // [2][4096]
  int t = threadIdx.x;
  int l = t & 63, l15 = l & 15, lg = l >> 4;
  int wid = t >> 6, wr = wid >> 1, wc = wid & 1;
  int bid = blockIdx.x;
  int xcd = bid & 7, idx = bid >> 3;
  int mi = (xcd & 3) * 8 + (idx >> 3);   // 0..31
  int ni = (xcd >> 2) * 8 + (idx & 7);   // 0..15
  int m0 = mi * 128, n0 = ni * 128;
  const u16* W = W0;
  u16* Ob = O0;
  if (MODE == 0) {
    if (blockIdx.y == 1) { W = W1; Ob = O1; }
    else if (blockIdx.y == 2) { W = W2; Ob = O2; }
  }
  const u16* Ag = A + (size_t)m0 * DIMD;
  const u16* Wg = W + (size_t)n0 * DIMD;
  int r0 = t >> 2, ch = (t & 3) * 8;

  f32x4 acc[4][4];
#pragma unroll
  for (int a1 = 0; a1 < 4; a1++)
#pragma unroll
    for (int b1 = 0; b1 < 4; b1++) acc[a1][b1] = (f32x4){0.f, 0.f, 0.f, 0.f};

  auto stage = [&](int buf, int kb) {
    int k0 = kb * 32;
    gld16(Ag + (size_t)r0 * DIMD + k0 + ch,        &lA[buf * 4096 + t * 8]);
    gld16(Ag + (size_t)(r0 + 64) * DIMD + k0 + ch, &lA[buf * 4096 + (t + 256) * 8]);
    gld16(Wg + (size_t)r0 * DIMD + k0 + ch,        &lB[buf * 4096 + t * 8]);
    gld16(Wg + (size_t)(r0 + 64) * DIMD + k0 + ch, &lB[buf * 4096 + (t + 256) * 8]);
  };

  stage(0, 0);
  __syncthreads();
#pragma unroll 2
  for (int kb = 0; kb < DIMD / 32; kb++) {
    if (kb + 1 < DIMD / 32) stage((kb + 1) & 1, kb + 1);
    int buf = kb & 1;
    s16x8 af[4], bfr[4];
#pragma unroll
    for (int rb = 0; rb < 4; rb++)
      af[rb] = *(const s16x8*)&lA[buf * 4096 + (wr * 64 + rb * 16 + l15) * 32 + lg * 8];
#pragma unroll
    for (int cb = 0; cb < 4; cb++)
      bfr[cb] = *(const s16x8*)&lB[buf * 4096 + (wc * 64 + cb * 16 + l15) * 32 + lg * 8];
#pragma unroll
    for (int rb = 0; rb < 4; rb++)
#pragma unroll
      for (int cb = 0; cb < 4; cb++)
        acc[rb][cb] = MFMA16(af[rb], bfr[cb], acc[rb][cb], 0, 0, 0);
    __syncthreads();
  }

  if (MODE == 0 && blockIdx.y == 2) {
    // ---- V epilogue: rotation-addressed transpose, write Vt (b,h,dh,s) ----
#pragma unroll
    for (int rb = 0; rb < 4; rb++)
#pragma unroll
      for (int cb = 0; cb < 4; cb++)
#pragma unroll
        for (int i = 0; i < 4; i++) {
          int row = wr * 64 + rb * 16 + lg * 4 + i;
          int col = wc * 64 + cb * 16 + l15;
          SM[row * 128 + ((col + row) & 127)] = f2bf(acc[rb][cb][i]);
        }
    __syncthreads();
    int b = m0 >> 11, s0 = m0 & (SQ - 1), h = n0 >> 7;
    int dh = t >> 1, sc = (t & 1) * 64;
    u16* dst = Ob + ((size_t)(b * NH + h) * HD + dh) * SQ + s0 + sc;
#pragma unroll
    for (int c8 = 0; c8 < 8; c8++) {
      u16x8 o;
#pragma unroll
      for (int e = 0; e < 8; e++) {
        int row = sc + c8 * 8 + e;
        o[e] = SM[row * 128 + ((dh + row) & 127)];
      }
      *(u16x8*)(dst + c8 * 8) = o;
    }
    return;
  }

#pragma unroll
  for (int rb = 0; rb < 4; rb++) {
#pragma unroll
    for (int cb = 0; cb < 4; cb++) {
#pragma unroll
      for (int i = 0; i < 4; i++) {
        float v = acc[rb][cb][i];
        int mm = m0 + wr * 64 + rb * 16 + lg * 4 + i;
        int nn = n0 + wc * 64 + cb * 16 + l15;
        if (MODE == 0) {
          int b = mm >> 11, s2 = mm & (SQ - 1), h = nn >> 7, dh = nn & (HD - 1);
          Ob[((size_t)(b * NH + h) * SQ + s2) * HD + dh] = f2bf(v);
        } else {
          Ofp[(size_t)mm * DIMD + nn] = v;
        }
      }
    }
  }
}

// ---------------- flash attention (swapped QK^T, 32 q-rows/wave, KBLK=32) ---
// LDS 40KB (Ksh 16 + Vsh 16 + Pl 8) -> 4 blocks/CU (was 80KB -> 2/CU).
// Pl rows are 64B: swizzle mask (l15&3)<<4 (bits 4-5, stays in-row,
// bijective; writes land 4 lanes/8B-slot = 2/bank = free). Vsh rows 64B:
// linear layout already spreads banks.
__global__ __launch_bounds__(256, 4) void attn_kernel(
    const u16* __restrict__ Q, const u16* __restrict__ K,
    const u16* __restrict__ Vt, u16* __restrict__ Aout) {
  __shared__ alignas(16) u16 Ksh[2][KBLK * HD];   // 2 x 8 KB
  __shared__ alignas(16) u16 Vsh[2][HD * KBLK];   // 2 x 8 KB
  __shared__ alignas(16) u16 Pl[4][32 * KBLK];    // 8 KB (per-wave, swizzled)
  int t = threadIdx.x;
  int wid = t >> 6, l = t & 63, l15 = l & 15, lg = l >> 4;
  int orig = blockIdx.x;
  int bid = (orig & 7) * 64 + (orig >> 3);
  int qb = bid & 15, bh = bid >> 4;
  int q0 = qb * QBLK + wid * 32;
  const u16* Qb = Q + ((size_t)bh * SQ + q0) * HD;
  const u16* Kb = K + (size_t)bh * SQ * HD;
  const u16* Vb = Vt + (size_t)bh * HD * SQ;

  s16x8 qf[2][4];
#pragma unroll
  for (int mq = 0; mq < 2; mq++)
#pragma unroll
    for (int ks = 0; ks < 4; ks++)
      qf[mq][ks] = *(const s16x8*)(Qb + (size_t)(mq * 16 + l15) * HD + ks * 32 + lg * 8);

  // staging: 256 thr x 16B x 2 passes per 8KB tile
  int od[2], kro[2], kco[2], vro[2], vco[2];
#pragma unroll
  for (int p2 = 0; p2 < 2; p2++) {
    int off = t * 16 + p2 * 4096;
    od[p2] = off;
    kro[p2] = off >> 8; kco[p2] = (off & 255) ^ ((kro[p2] & 7) << 4);
    vro[p2] = off >> 6; vco[p2] = off & 63;   // 64B rows, linear
  }

  auto stage = [&](int buf, int kb) {
    const u16* Kt = Kb + (size_t)kb * KBLK * HD;
    const u16* Vs = Vb + kb * KBLK;
#pragma unroll
    for (int p2 = 0; p2 < 2; p2++)
      gld16(Kt + (size_t)kro[p2] * HD + (kco[p2] >> 1), &Ksh[buf][od[p2] >> 1]);
#pragma unroll
    for (int p2 = 0; p2 < 2; p2++)
      gld16(Vs + (size_t)vro[p2] * SQ + (vco[p2] >> 1), &Vsh[buf][od[p2] >> 1]);
  };

  f32x4 acc[2][8];
#pragma unroll
  for (int mq = 0; mq < 2; mq++)
#pragma unroll
    for (int i = 0; i < 8; i++) acc[mq][i] = (f32x4){0.f, 0.f, 0.f, 0.f};
  float m[2] = {-3.0e38f, -3.0e38f}, lsum[2] = {0.f, 0.f};

  stage(0, 0);
  __syncthreads();

#pragma unroll 1
  for (int kb = 0; kb < SQ / KBLK; kb++) {
    int cur = kb & 1;
    if (kb + 1 < SQ / KBLK) stage(cur ^ 1, kb + 1);
    // ---- S^T = K . Q^T : rows k (cb*16+lg*4+i), cols q (mq*16 + l15) ----
    f32x4 sa[2][2];
#pragma unroll
    for (int mq = 0; mq < 2; mq++)
#pragma unroll
      for (int cb = 0; cb < 2; cb++) sa[mq][cb] = (f32x4){0.f, 0.f, 0.f, 0.f};
    __builtin_amdgcn_s_setprio(1);
#pragma unroll
    for (int ks = 0; ks < 4; ks++) {
#pragma unroll
      for (int cb = 0; cb < 2; cb++) {
        int r = cb * 16 + l15;
        int off = r * 256 + ((ks * 64 + lg * 16) ^ ((r & 7) << 4));
        s16x8 kf = *(const s16x8*)((const char*)&Ksh[cur][0] + off);
        sa[0][cb] = MFMA16(kf, qf[0][ks], sa[0][cb], 0, 0, 0);
        sa[1][cb] = MFMA16(kf, qf[1][ks], sa[1][cb], 0, 0, 0);
      }
    }
    __builtin_amdgcn_s_setprio(0);
    // ---- row stats ----
    float rm[2];
#pragma unroll
    for (int mq = 0; mq < 2; mq++) {
      float r2 = sa[mq][0][0];
#pragma unroll
      for (int cb = 0; cb < 2; cb++)
#pragma unroll
        for (int i = 0; i < 4; i++) r2 = fmaxf(r2, sa[mq][cb][i]);
      r2 = fmaxf(r2, __shfl_xor(r2, 16));
      r2 = fmaxf(r2, __shfl_xor(r2, 32));
      rm[mq] = r2;
    }
    if (!__all(rm[0] <= m[0] + 8.0f && rm[1] <= m[1] + 8.0f)) {  // defer-max
#pragma unroll
      for (int mq = 0; mq < 2; mq++) {
        float mn = fmaxf(m[mq], rm[mq]);
        float al = __expf(m[mq] - mn);
        m[mq] = mn;
        float alq[4];
#pragma unroll
        for (int i = 0; i < 4; i++) alq[i] = __shfl(al, lg * 4 + i, 16);
#pragma unroll
        for (int c2 = 0; c2 < 8; c2++)
#pragma unroll
          for (int i = 0; i < 4; i++) acc[mq][c2][i] *= alq[i];
        lsum[mq] *= al;
      }
    }
#pragma unroll
    for (int mq = 0; mq < 2; mq++) {
      float ps = 0.f;
#pragma unroll
      for (int cb = 0; cb < 2; cb++)
#pragma unroll
        for (int i = 0; i < 4; i++) {
          sa[mq][cb][i] = __expf(sa[mq][cb][i] - m[mq]);
          ps += sa[mq][cb][i];
        }
      ps += __shfl_xor(ps, 16);
      ps += __shfl_xor(ps, 32);
      lsum[mq] += ps;
    }
    // ---- P -> per-wave LDS: row q (64B), swizzle bits 4-5 ----
#pragma unroll
    for (int mq = 0; mq < 2; mq++)
#pragma unroll
      for (int cb = 0; cb < 2; cb++) {
        u32 lo = (u32)f2bf(sa[mq][cb][0]) | ((u32)f2bf(sa[mq][cb][1]) << 16);
        u32 hi = (u32)f2bf(sa[mq][cb][2]) | ((u32)f2bf(sa[mq][cb][3]) << 16);
        int off = (mq * 16 + l15) * 64 + ((cb * 32 + lg * 8) ^ ((l15 & 3) << 4));
        *(uint2*)((char*)&Pl[wid][0] + off) = make_uint2(lo, hi);
      }
    s16x8 pf[2];
#pragma unroll
    for (int mq = 0; mq < 2; mq++) {
      int off = (mq * 16 + l15) * 64 + ((lg * 16) ^ ((l15 & 3) << 4));
      pf[mq] = *(const s16x8*)((const char*)&Pl[wid][0] + off);
    }
    // ---- PV: out 32 q-rows x 128 dh ----
    __builtin_amdgcn_s_setprio(1);
#pragma unroll
    for (int c2 = 0; c2 < 8; c2++) {
      int r = c2 * 16 + l15;
      int off = r * 64 + lg * 16;
      s16x8 vf = *(const s16x8*)((const char*)&Vsh[cur][0] + off);
      acc[0][c2] = MFMA16(pf[0], vf, acc[0][c2], 0, 0, 0);
      acc[1][c2] = MFMA16(pf[1], vf, acc[1][c2], 0, 0, 0);
    }
    __builtin_amdgcn_s_setprio(0);
    __syncthreads();
  }
  int b = bh >> 4, h = bh & (NH - 1);
#pragma unroll
  for (int mq = 0; mq < 2; mq++) {
    float rin = 1.0f / lsum[mq];
    float rq[4];
#pragma unroll
    for (int i = 0; i < 4; i++) rq[i] = __shfl(rin, lg * 4 + i, 16);
#pragma unroll
    for (int c2 = 0; c2 < 8; c2++) {
#pragma unroll
      for (int i = 0; i < 4; i++) {
        int q = q0 + mq * 16 + lg * 4 + i;
        int dh = c2 * 16 + l15;
        Aout[((size_t)b * SQ + q) * DIMD + h * HD + dh] = f2bf(acc[mq][c2][i] * rq[i]);
      }
    }
  }
}

extern "C" void kernel_launch(void* const* d_in, const int* in_sizes, int n_in,
                              void* d_out, int out_size, void* d_ws, size_t ws_size,
                              hipStream_t stream) {
  (void)in_sizes; (void)n_in; (void)out_size; (void)ws_size;
  const float* x    = (const float*)d_in[0];
  const float* wq   = (const float*)d_in[1];
  const float* wk   = (const float*)d_in[2];
  const float* wv   = (const float*)d_in[3];
  const float* wo   = (const float*)d_in[4];
  const float* cosT = (const float*)d_in[5];
  const float* sinT = (const float*)d_in[6];
  float* out = (float*)d_out;

  char* p = (char*)d_ws;
  const size_t SZ_MD = (size_t)MR * DIMD * 2;    // 16.78 MB
  const size_t SZ_W  = (size_t)DIMD * DIMD * 2;  // 8.39 MB
  u16* xb   = (u16*)p; p += SZ_MD;
  u16* wqb  = (u16*)p; p += SZ_W;   // wq,wk,wv,wo contiguous (cvt_all)
  u16* wkb  = (u16*)p; p += SZ_W;
  u16* wvb  = (u16*)p; p += SZ_W;
  u16* wob  = (u16*)p; p += SZ_W;
  u16* Qraw = (u16*)p; p += SZ_MD;
  u16* Kraw = (u16*)p; p += SZ_MD;
  u16* Qr   = (u16*)p; p += SZ_MD;
  u16* Kr   = (u16*)p; p += SZ_MD;
  u16* Vt   = (u16*)p; p += SZ_MD;
  u16* attnout = Qraw;  // Qraw dead after rope; reuse

  cvt_all<<<dim3(512, 5), 256, 0, stream>>>(x, wq, wk, wv, wo, xb, wqb);

  gemm_bt<0><<<dim3(512, 3), 256, 0, stream>>>(xb, wqb, wkb, wvb, Qraw, Kraw, Vt, nullptr);
  rope_kernel<<<dim3(16384, 2), 256, 0, stream>>>(Qraw, Kraw, Qr, Kr, cosT, sinT);
  attn_kernel<<<512, 256, 0, stream>>>(Qr, Kr, Vt, attnout);
  gemm_bt<1><<<dim3(512, 1), 256, 0, stream>>>(attnout, wob, nullptr, nullptr,
                                               nullptr, nullptr, nullptr, out);
}

// Round 16
// 305.373 us; speedup vs baseline: 1.2392x; 1.2392x over previous
//
#include <hip/hip_runtime.h>

#define SQ   2048
#define DIMD 2048
#define NH   16
#define HD   128
#define MR   4096   // B*S
#define QBLK 128
#define KBLK 64

using u16 = unsigned short;
using u32 = unsigned int;
using s16x8 = __attribute__((ext_vector_type(8))) short;
using u16x8 = __attribute__((ext_vector_type(8))) unsigned short;
using f32x4 = __attribute__((ext_vector_type(4))) float;
using as3u  = __attribute__((address_space(3))) u32;
using as1u  = __attribute__((address_space(1))) u32;

__device__ __forceinline__ u16 f2bf(float f) {
  u32 x = __float_as_uint(f);
  return (u16)((x + 0x7fffu + ((x >> 16) & 1u)) >> 16);
}
__device__ __forceinline__ float bf2f(u16 u) {
  return __uint_as_float(((u32)u) << 16);
}
__device__ __forceinline__ void gld16(const void* g, void* l) {
  __builtin_amdgcn_global_load_lds((as1u*)g, (as3u*)l, 16, 0, 0);
}
#define MFMA16 __builtin_amdgcn_mfma_f32_16x16x32_bf16

// ---------------- fp32 -> bf16 convert: x + 4 weights, ONE launch -----------
__global__ __launch_bounds__(256) void cvt_all(
    const float* __restrict__ x,
    const float* __restrict__ w0, const float* __restrict__ w1,
    const float* __restrict__ w2, const float* __restrict__ w3,
    u16* __restrict__ xb, u16* __restrict__ wb) {
  int y = blockIdx.y;
  const float* s;
  u16* dst;
  int n4;
  if (y == 4) { s = x; dst = xb; n4 = MR * DIMD / 4; }
  else {
    s = (y == 0) ? w0 : (y == 1) ? w1 : (y == 2) ? w2 : w3;
    dst = wb + (size_t)y * DIMD * DIMD;
    n4 = DIMD * DIMD / 4;
  }
  int i = blockIdx.x * 256 + threadIdx.x;
  int st = gridDim.x * 256;
  for (; i < n4; i += st) {
    float4 v = ((const float4*)s)[i];
    u32 lo = (u32)f2bf(v.x) | ((u32)f2bf(v.y) << 16);
    u32 hi = (u32)f2bf(v.z) | ((u32)f2bf(v.w) << 16);
    ((uint2*)dst)[i] = make_uint2(lo, hi);
  }
}

// ---------------- RoPE (1 wave = 1 row of 128) ----------------
__global__ __launch_bounds__(256) void rope_kernel(
    const u16* __restrict__ Qin, const u16* __restrict__ Kin,
    u16* __restrict__ Qout, u16* __restrict__ Kout,
    const float* __restrict__ cosT, const float* __restrict__ sinT) {
  int ten = blockIdx.y;
  const u16* in = ten ? Kin : Qin;
  u16* outp     = ten ? Kout : Qout;
  float scl     = ten ? 1.0f : 0.08838834764831845f;  // fold 1/sqrt(DH) into Q
  int row = blockIdx.x * 4 + (threadIdx.x >> 6);
  int j   = threadIdx.x & 63;
  int s   = row & (SQ - 1);
  const u16* r = in + (size_t)row * HD;
  u16* w = outp + (size_t)row * HD;
  float c  = cosT[s * HD + j];
  float si = sinT[s * HD + j];
  float a  = bf2f(r[j]);
  float b  = bf2f(r[j + 64]);
  float ev = bf2f(r[2 * j]);
  float od = bf2f(r[2 * j + 1]);
  w[j]      = f2bf((a * c - od * si) * scl);
  w[j + 64] = f2bf((b * c + ev * si) * scl);
}

// ---------------- GEMM C = A(M,K) * W(N,K)^T  (m97 structure) ---------------
// 2D-chunked XCD swizzle: xcd = bid&7 owns an 8mi x 8ni square (A-panels 4MB
// + W-panels 4MB in its L2, 8x reuse per fetch; A shared across the 3 y's).
// MODE 0: QKV dim3(512,3); y=0,1 scatter (b,h,s,dh); y=2 (V) rotation-
//         addressed 32KB-alias transpose -> Vt (b,h,dh,s).
// MODE 1: O-proj -> fp32 row-major.
template <int MODE>
__global__ __launch_bounds__(256, 5) void gemm_bt(
    const u16* __restrict__ A,
    const u16* __restrict__ W0, const u16* __restrict__ W1, const u16* __restrict__ W2,
    u16* __restrict__ O0, u16* __restrict__ O1, u16* __restrict__ O2,
    float* __restrict__ Ofp) {
  __shared__ alignas(16) u16 SM[16384];   // 32 KB: staging; aliased by V-epi
  u16* lA = SM;          // [2][4096]
  u16* lB = SM + 8192;   // [2][4096]
  int t = threadIdx.x;
  int l = t & 63, l15 = l & 15, lg = l >> 4;
  int wid = t >> 6, wr = wid >> 1, wc = wid & 1;
  int bid = blockIdx.x;
  int xcd = bid & 7, idx = bid >> 3;
  int mi = (xcd & 3) * 8 + (idx >> 3);   // 0..31
  int ni = (xcd >> 2) * 8 + (idx & 7);   // 0..15
  int m0 = mi * 128, n0 = ni * 128;
  const u16* W = W0;
  u16* Ob = O0;
  if (MODE == 0) {
    if (blockIdx.y == 1) { W = W1; Ob = O1; }
    else if (blockIdx.y == 2) { W = W2; Ob = O2; }
  }
  const u16* Ag = A + (size_t)m0 * DIMD;
  const u16* Wg = W + (size_t)n0 * DIMD;
  int r0 = t >> 2, ch = (t & 3) * 8;

  f32x4 acc[4][4];
#pragma unroll
  for (int a1 = 0; a1 < 4; a1++)
#pragma unroll
    for (int b1 = 0; b1 < 4; b1++) acc[a1][b1] = (f32x4){0.f, 0.f, 0.f, 0.f};

  auto stage = [&](int buf, int kb) {
    int k0 = kb * 32;
    gld16(Ag + (size_t)r0 * DIMD + k0 + ch,        &lA[buf * 4096 + t * 8]);
    gld16(Ag + (size_t)(r0 + 64) * DIMD + k0 + ch, &lA[buf * 4096 + (t + 256) * 8]);
    gld16(Wg + (size_t)r0 * DIMD + k0 + ch,        &lB[buf * 4096 + t * 8]);
    gld16(Wg + (size_t)(r0 + 64) * DIMD + k0 + ch, &lB[buf * 4096 + (t + 256) * 8]);
  };

  stage(0, 0);
  __syncthreads();
#pragma unroll 2
  for (int kb = 0; kb < DIMD / 32; kb++) {
    if (kb + 1 < DIMD / 32) stage((kb + 1) & 1, kb + 1);
    int buf = kb & 1;
    s16x8 af[4], bfr[4];
#pragma unroll
    for (int rb = 0; rb < 4; rb++)
      af[rb] = *(const s16x8*)&lA[buf * 4096 + (wr * 64 + rb * 16 + l15) * 32 + lg * 8];
#pragma unroll
    for (int cb = 0; cb < 4; cb++)
      bfr[cb] = *(const s16x8*)&lB[buf * 4096 + (wc * 64 + cb * 16 + l15) * 32 + lg * 8];
#pragma unroll
    for (int rb = 0; rb < 4; rb++)
#pragma unroll
      for (int cb = 0; cb < 4; cb++)
        acc[rb][cb] = MFMA16(af[rb], bfr[cb], acc[rb][cb], 0, 0, 0);
    __syncthreads();
  }

  if (MODE == 0 && blockIdx.y == 2) {
    // ---- V epilogue: rotation-addressed transpose, write Vt (b,h,dh,s) ----
#pragma unroll
    for (int rb = 0; rb < 4; rb++)
#pragma unroll
      for (int cb = 0; cb < 4; cb++)
#pragma unroll
        for (int i = 0; i < 4; i++) {
          int row = wr * 64 + rb * 16 + lg * 4 + i;
          int col = wc * 64 + cb * 16 + l15;
          SM[row * 128 + ((col + row) & 127)] = f2bf(acc[rb][cb][i]);
        }
    __syncthreads();
    int b = m0 >> 11, s0 = m0 & (SQ - 1), h = n0 >> 7;
    int dh = t >> 1, sc = (t & 1) * 64;
    u16* dst = Ob + ((size_t)(b * NH + h) * HD + dh) * SQ + s0 + sc;
#pragma unroll
    for (int c8 = 0; c8 < 8; c8++) {
      u16x8 o;
#pragma unroll
      for (int e = 0; e < 8; e++) {
        int row = sc + c8 * 8 + e;
        o[e] = SM[row * 128 + ((dh + row) & 127)];
      }
      *(u16x8*)(dst + c8 * 8) = o;
    }
    return;
  }

#pragma unroll
  for (int rb = 0; rb < 4; rb++) {
#pragma unroll
    for (int cb = 0; cb < 4; cb++) {
#pragma unroll
      for (int i = 0; i < 4; i++) {
        float v = acc[rb][cb][i];
        int mm = m0 + wr * 64 + rb * 16 + lg * 4 + i;
        int nn = n0 + wc * 64 + cb * 16 + l15;
        if (MODE == 0) {
          int b = mm >> 11, s2 = mm & (SQ - 1), h = nn >> 7, dh = nn & (HD - 1);
          Ob[((size_t)(b * NH + h) * SQ + s2) * HD + dh] = f2bf(v);
        } else {
          Ofp[(size_t)mm * DIMD + nn] = v;
        }
      }
    }
  }
}

// ---------------- flash attention (swapped QK^T, 32 q-rows per wave) --------
// PROVEN r14 version: KBLK=64, 80 KB LDS, 2 blocks/CU (~80 us). KBLK=32
// regressed 2.4x (more barriers, 8-way Vsh conflicts) -- reverted.
__global__ __launch_bounds__(256, 2) void attn_kernel(
    const u16* __restrict__ Q, const u16* __restrict__ K,
    const u16* __restrict__ Vt, u16* __restrict__ Aout) {
  __shared__ alignas(16) u16 Ksh[2][KBLK * HD];   // 2 x 16 KB
  __shared__ alignas(16) u16 Vsh[2][HD * KBLK];   // 2 x 16 KB
  __shared__ alignas(16) u16 Pl[4][32 * KBLK];    // 16 KB (per-wave, swizzled)
  int t = threadIdx.x;
  int wid = t >> 6, l = t & 63, l15 = l & 15, lg = l >> 4;
  int orig = blockIdx.x;
  int bid = (orig & 7) * 64 + (orig >> 3);
  int qb = bid & 15, bh = bid >> 4;
  int q0 = qb * QBLK + wid * 32;
  const u16* Qb = Q + ((size_t)bh * SQ + q0) * HD;
  const u16* Kb = K + (size_t)bh * SQ * HD;
  const u16* Vb = Vt + (size_t)bh * HD * SQ;

  s16x8 qf[2][4];
#pragma unroll
  for (int mq = 0; mq < 2; mq++)
#pragma unroll
    for (int ks = 0; ks < 4; ks++)
      qf[mq][ks] = *(const s16x8*)(Qb + (size_t)(mq * 16 + l15) * HD + ks * 32 + lg * 8);

  int od[4], kro[4], kco[4], vro[4], vco[4];
#pragma unroll
  for (int p2 = 0; p2 < 4; p2++) {
    int off = t * 16 + p2 * 4096;
    od[p2] = off;
    kro[p2] = off >> 8; kco[p2] = (off & 255) ^ ((kro[p2] & 7) << 4);
    vro[p2] = off >> 7; vco[p2] = (off & 127) ^ ((vro[p2] & 7) << 4);
  }

  auto stage = [&](int buf, int kb) {
    const u16* Kt = Kb + (size_t)kb * KBLK * HD;
    const u16* Vs = Vb + kb * KBLK;
#pragma unroll
    for (int p2 = 0; p2 < 4; p2++)
      gld16(Kt + (size_t)kro[p2] * HD + (kco[p2] >> 1), &Ksh[buf][od[p2] >> 1]);
#pragma unroll
    for (int p2 = 0; p2 < 4; p2++)
      gld16(Vs + (size_t)vro[p2] * SQ + (vco[p2] >> 1), &Vsh[buf][od[p2] >> 1]);
  };

  f32x4 acc[2][8];
#pragma unroll
  for (int mq = 0; mq < 2; mq++)
#pragma unroll
    for (int i = 0; i < 8; i++) acc[mq][i] = (f32x4){0.f, 0.f, 0.f, 0.f};
  float m[2] = {-3.0e38f, -3.0e38f}, lsum[2] = {0.f, 0.f};

  stage(0, 0);
  __syncthreads();

#pragma unroll 1
  for (int kb = 0; kb < SQ / KBLK; kb++) {
    int cur = kb & 1;
    if (kb + 1 < SQ / KBLK) stage(cur ^ 1, kb + 1);
    f32x4 sa[2][4];
#pragma unroll
    for (int mq = 0; mq < 2; mq++)
#pragma unroll
      for (int cb = 0; cb < 4; cb++) sa[mq][cb] = (f32x4){0.f, 0.f, 0.f, 0.f};
    __builtin_amdgcn_s_setprio(1);
#pragma unroll
    for (int ks = 0; ks < 4; ks++) {
#pragma unroll
      for (int cb = 0; cb < 4; cb++) {
        int r = cb * 16 + l15;
        int off = r * 256 + ((ks * 64 + lg * 16) ^ ((r & 7) << 4));
        s16x8 kf = *(const s16x8*)((const char*)&Ksh[cur][0] + off);
        sa[0][cb] = MFMA16(kf, qf[0][ks], sa[0][cb], 0, 0, 0);
        sa[1][cb] = MFMA16(kf, qf[1][ks], sa[1][cb], 0, 0, 0);
      }
    }
    __builtin_amdgcn_s_setprio(0);
    float rm[2];
#pragma unroll
    for (int mq = 0; mq < 2; mq++) {
      float r2 = sa[mq][0][0];
#pragma unroll
      for (int cb = 0; cb < 4; cb++)
#pragma unroll
        for (int i = 0; i < 4; i++) r2 = fmaxf(r2, sa[mq][cb][i]);
      r2 = fmaxf(r2, __shfl_xor(r2, 16));
      r2 = fmaxf(r2, __shfl_xor(r2, 32));
      rm[mq] = r2;
    }
    if (!__all(rm[0] <= m[0] + 8.0f && rm[1] <= m[1] + 8.0f)) {  // defer-max
#pragma unroll
      for (int mq = 0; mq < 2; mq++) {
        float mn = fmaxf(m[mq], rm[mq]);
        float al = __expf(m[mq] - mn);
        m[mq] = mn;
        float alq[4];
#pragma unroll
        for (int i = 0; i < 4; i++) alq[i] = __shfl(al, lg * 4 + i, 16);
#pragma unroll
        for (int c2 = 0; c2 < 8; c2++)
#pragma unroll
          for (int i = 0; i < 4; i++) acc[mq][c2][i] *= alq[i];
        lsum[mq] *= al;
      }
    }
#pragma unroll
    for (int mq = 0; mq < 2; mq++) {
      float ps = 0.f;
#pragma unroll
      for (int cb = 0; cb < 4; cb++)
#pragma unroll
        for (int i = 0; i < 4; i++) {
          sa[mq][cb][i] = __expf(sa[mq][cb][i] - m[mq]);
          ps += sa[mq][cb][i];
        }
      ps += __shfl_xor(ps, 16);
      ps += __shfl_xor(ps, 32);
      lsum[mq] += ps;
    }
#pragma unroll
    for (int mq = 0; mq < 2; mq++)
#pragma unroll
      for (int cb = 0; cb < 4; cb++) {
        u32 lo = (u32)f2bf(sa[mq][cb][0]) | ((u32)f2bf(sa[mq][cb][1]) << 16);
        u32 hi = (u32)f2bf(sa[mq][cb][2]) | ((u32)f2bf(sa[mq][cb][3]) << 16);
        int off = (mq * 16 + l15) * 128 + ((cb * 32 + lg * 8) ^ ((l15 & 7) << 4));
        *(uint2*)((char*)&Pl[wid][0] + off) = make_uint2(lo, hi);
      }
    s16x8 pf[2][2];
#pragma unroll
    for (int mq = 0; mq < 2; mq++)
#pragma unroll
      for (int k2 = 0; k2 < 2; k2++) {
        int off = (mq * 16 + l15) * 128 + ((k2 * 64 + lg * 16) ^ ((l15 & 7) << 4));
        pf[mq][k2] = *(const s16x8*)((const char*)&Pl[wid][0] + off);
      }
    __builtin_amdgcn_s_setprio(1);
#pragma unroll
    for (int c2 = 0; c2 < 8; c2++) {
#pragma unroll
      for (int k2 = 0; k2 < 2; k2++) {
        int r = c2 * 16 + l15;
        int off = r * 128 + ((k2 * 64 + lg * 16) ^ ((r & 7) << 4));
        s16x8 vf = *(const s16x8*)((const char*)&Vsh[cur][0] + off);
        acc[0][c2] = MFMA16(pf[0][k2], vf, acc[0][c2], 0, 0, 0);
        acc[1][c2] = MFMA16(pf[1][k2], vf, acc[1][c2], 0, 0, 0);
      }
    }
    __builtin_amdgcn_s_setprio(0);
    __syncthreads();
  }
  int b = bh >> 4, h = bh & (NH - 1);
#pragma unroll
  for (int mq = 0; mq < 2; mq++) {
    float rin = 1.0f / lsum[mq];
    float rq[4];
#pragma unroll
    for (int i = 0; i < 4; i++) rq[i] = __shfl(rin, lg * 4 + i, 16);
#pragma unroll
    for (int c2 = 0; c2 < 8; c2++) {
#pragma unroll
      for (int i = 0; i < 4; i++) {
        int q = q0 + mq * 16 + lg * 4 + i;
        int dh = c2 * 16 + l15;
        Aout[((size_t)b * SQ + q) * DIMD + h * HD + dh] = f2bf(acc[mq][c2][i] * rq[i]);
      }
    }
  }
}

extern "C" void kernel_launch(void* const* d_in, const int* in_sizes, int n_in,
                              void* d_out, int out_size, void* d_ws, size_t ws_size,
                              hipStream_t stream) {
  (void)in_sizes; (void)n_in; (void)out_size; (void)ws_size;
  const float* x    = (const float*)d_in[0];
  const float* wq   = (const float*)d_in[1];
  const float* wk   = (const float*)d_in[2];
  const float* wv   = (const float*)d_in[3];
  const float* wo   = (const float*)d_in[4];
  const float* cosT = (const float*)d_in[5];
  const float* sinT = (const float*)d_in[6];
  float* out = (float*)d_out;

  char* p = (char*)d_ws;
  const size_t SZ_MD = (size_t)MR * DIMD * 2;    // 16.78 MB
  const size_t SZ_W  = (size_t)DIMD * DIMD * 2;  // 8.39 MB
  u16* xb   = (u16*)p; p += SZ_MD;
  u16* wqb  = (u16*)p; p += SZ_W;   // wq,wk,wv,wo contiguous (cvt_all)
  u16* wkb  = (u16*)p; p += SZ_W;
  u16* wvb  = (u16*)p; p += SZ_W;
  u16* wob  = (u16*)p; p += SZ_W;
  u16* Qraw = (u16*)p; p += SZ_MD;
  u16* Kraw = (u16*)p; p += SZ_MD;
  u16* Qr   = (u16*)p; p += SZ_MD;
  u16* Kr   = (u16*)p; p += SZ_MD;
  u16* Vt   = (u16*)p; p += SZ_MD;
  u16* attnout = Qraw;  // Qraw dead after rope; reuse

  cvt_all<<<dim3(512, 5), 256, 0, stream>>>(x, wq, wk, wv, wo, xb, wqb);

  gemm_bt<0><<<dim3(512, 3), 256, 0, stream>>>(xb, wqb, wkb, wvb, Qraw, Kraw, Vt, nullptr);
  rope_kernel<<<dim3(16384, 2), 256, 0, stream>>>(Qraw, Kraw, Qr, Kr, cosT, sinT);
  attn_kernel<<<512, 256, 0, stream>>>(Qr, Kr, Vt, attnout);
  gemm_bt<1><<<dim3(512, 1), 256, 0, stream>>>(attnout, wob, nullptr, nullptr,
                                               nullptr, nullptr, nullptr, out);
}

// Round 17
// 293.362 us; speedup vs baseline: 1.2899x; 1.0409x over previous
//
#include <hip/hip_runtime.h>

#define SQ   2048
#define DIMD 2048
#define NH   16
#define HD   128
#define MR   4096   // B*S
#define QBLK 128
#define KBLK 64

using u16 = unsigned short;
using u32 = unsigned int;
using s16x8 = __attribute__((ext_vector_type(8))) short;
using u16x8 = __attribute__((ext_vector_type(8))) unsigned short;
using f32x4 = __attribute__((ext_vector_type(4))) float;
using as3u  = __attribute__((address_space(3))) u32;
using as1u  = __attribute__((address_space(1))) u32;

__device__ __forceinline__ u16 f2bf(float f) {
  u32 x = __float_as_uint(f);
  return (u16)((x + 0x7fffu + ((x >> 16) & 1u)) >> 16);
}
__device__ __forceinline__ float bf2f(u16 u) {
  return __uint_as_float(((u32)u) << 16);
}
__device__ __forceinline__ void gld16(const void* g, void* l) {
  __builtin_amdgcn_global_load_lds((as1u*)g, (as3u*)l, 16, 0, 0);
}
#define MFMA16 __builtin_amdgcn_mfma_f32_16x16x32_bf16

// ---------------- fp32 -> bf16 convert: x + 4 weights, ONE launch -----------
__global__ __launch_bounds__(256) void cvt_all(
    const float* __restrict__ x,
    const float* __restrict__ w0, const float* __restrict__ w1,
    const float* __restrict__ w2, const float* __restrict__ w3,
    u16* __restrict__ xb, u16* __restrict__ wb) {
  int y = blockIdx.y;
  const float* s;
  u16* dst;
  int n4;
  if (y == 4) { s = x; dst = xb; n4 = MR * DIMD / 4; }
  else {
    s = (y == 0) ? w0 : (y == 1) ? w1 : (y == 2) ? w2 : w3;
    dst = wb + (size_t)y * DIMD * DIMD;
    n4 = DIMD * DIMD / 4;
  }
  int i = blockIdx.x * 256 + threadIdx.x;
  int st = gridDim.x * 256;
  for (; i < n4; i += st) {
    float4 v = ((const float4*)s)[i];
    u32 lo = (u32)f2bf(v.x) | ((u32)f2bf(v.y) << 16);
    u32 hi = (u32)f2bf(v.z) | ((u32)f2bf(v.w) << 16);
    ((uint2*)dst)[i] = make_uint2(lo, hi);
  }
}

// ---------------- RoPE (1 wave = 1 row of 128) ----------------
__global__ __launch_bounds__(256) void rope_kernel(
    const u16* __restrict__ Qin, const u16* __restrict__ Kin,
    u16* __restrict__ Qout, u16* __restrict__ Kout,
    const float* __restrict__ cosT, const float* __restrict__ sinT) {
  int ten = blockIdx.y;
  const u16* in = ten ? Kin : Qin;
  u16* outp     = ten ? Kout : Qout;
  float scl     = ten ? 1.0f : 0.08838834764831845f;  // fold 1/sqrt(DH) into Q
  int row = blockIdx.x * 4 + (threadIdx.x >> 6);
  int j   = threadIdx.x & 63;
  int s   = row & (SQ - 1);
  const u16* r = in + (size_t)row * HD;
  u16* w = outp + (size_t)row * HD;
  float c  = cosT[s * HD + j];
  float si = sinT[s * HD + j];
  float a  = bf2f(r[j]);
  float b  = bf2f(r[j + 64]);
  float ev = bf2f(r[2 * j]);
  float od = bf2f(r[2 * j + 1]);
  w[j]      = f2bf((a * c - od * si) * scl);
  w[j + 64] = f2bf((b * c + ev * si) * scl);
}

// ---------------- GEMM C = A(M,K) * W(N,K)^T ---------------------------------
// m97 128x128 geometry + TRIPLE-buffered LDS with counted vmcnt (T4):
// stage tile kt+2 while computing kt; per tile ONE {vmcnt(4); s_barrier} --
// tile kt+1's 4 loads proven complete, kt+2's 4 stay in flight across the
// barrier (never drain to 0 in steady state). Correctness of this schedule
// was proven in R6 (passed); R6's slowdown was 256-tile/1-block-CU occupancy,
// fixed here: 48 KB LDS -> 3 blocks/CU (12 waves). Tail: vmcnt(0) when no
// more stages. 2D-chunked XCD swizzle kept (FETCH 192->103 MB, r16).
// MODE 0: QKV dim3(512,3); y=0,1 scatter; y=2 (V) rotation-addressed
//         32KB-alias transpose -> Vt. MODE 1: O-proj fp32.
template <int MODE>
__global__ __launch_bounds__(256, 5) void gemm_bt(
    const u16* __restrict__ A,
    const u16* __restrict__ W0, const u16* __restrict__ W1, const u16* __restrict__ W2,
    u16* __restrict__ O0, u16* __restrict__ O1, u16* __restrict__ O2,
    float* __restrict__ Ofp) {
  __shared__ alignas(16) u16 SM[24576];   // 48 KB: lA[3][4096] + lB[3][4096]
  u16* lA = SM;            // 3 x 8 KB
  u16* lB = SM + 12288;    // 3 x 8 KB
  int t = threadIdx.x;
  int l = t & 63, l15 = l & 15, lg = l >> 4;
  int wid = t >> 6, wr = wid >> 1, wc = wid & 1;
  int bid = blockIdx.x;
  int xcd = bid & 7, idx = bid >> 3;
  int mi = (xcd & 3) * 8 + (idx >> 3);   // 0..31
  int ni = (xcd >> 2) * 8 + (idx & 7);   // 0..15
  int m0 = mi * 128, n0 = ni * 128;
  const u16* W = W0;
  u16* Ob = O0;
  if (MODE == 0) {
    if (blockIdx.y == 1) { W = W1; Ob = O1; }
    else if (blockIdx.y == 2) { W = W2; Ob = O2; }
  }
  const u16* Ag = A + (size_t)m0 * DIMD;
  const u16* Wg = W + (size_t)n0 * DIMD;
  int r0 = t >> 2, ch = (t & 3) * 8;

  f32x4 acc[4][4];
#pragma unroll
  for (int a1 = 0; a1 < 4; a1++)
#pragma unroll
    for (int b1 = 0; b1 < 4; b1++) acc[a1][b1] = (f32x4){0.f, 0.f, 0.f, 0.f};

  auto stage = [&](int buf, int kb) {
    int k0 = kb * 32;
    gld16(Ag + (size_t)r0 * DIMD + k0 + ch,        &lA[buf * 4096 + t * 8]);
    gld16(Ag + (size_t)(r0 + 64) * DIMD + k0 + ch, &lA[buf * 4096 + (t + 256) * 8]);
    gld16(Wg + (size_t)r0 * DIMD + k0 + ch,        &lB[buf * 4096 + t * 8]);
    gld16(Wg + (size_t)(r0 + 64) * DIMD + k0 + ch, &lB[buf * 4096 + (t + 256) * 8]);
  };

  const int NKT = DIMD / 32;  // 64 K-tiles
  stage(0, 0);
  stage(1, 1);
  asm volatile("s_waitcnt vmcnt(4)" ::: "memory");  // tile 0 resident
  __builtin_amdgcn_s_barrier();

  int bcur = 0;
#pragma unroll 1
  for (int kt = 0; kt < NKT; kt++) {
    if (kt + 2 < NKT) {
      int bnext = bcur + 2; if (bnext > 2) bnext -= 3;
      stage(bnext, kt + 2);
    }
    s16x8 af[4], bfr[4];
#pragma unroll
    for (int rb = 0; rb < 4; rb++)
      af[rb] = *(const s16x8*)&lA[bcur * 4096 + (wr * 64 + rb * 16 + l15) * 32 + lg * 8];
#pragma unroll
    for (int cb = 0; cb < 4; cb++)
      bfr[cb] = *(const s16x8*)&lB[bcur * 4096 + (wc * 64 + cb * 16 + l15) * 32 + lg * 8];
#pragma unroll
    for (int rb = 0; rb < 4; rb++)
#pragma unroll
      for (int cb = 0; cb < 4; cb++)
        acc[rb][cb] = MFMA16(af[rb], bfr[cb], acc[rb][cb], 0, 0, 0);
    if (kt + 1 < NKT) {
      if (kt + 2 < NKT) asm volatile("s_waitcnt vmcnt(4)" ::: "memory");
      else              asm volatile("s_waitcnt vmcnt(0)" ::: "memory");
      __builtin_amdgcn_s_barrier();
    }
    bcur = bcur + 1; if (bcur > 2) bcur -= 3;
  }

  if (MODE == 0 && blockIdx.y == 2) {
    // ---- V epilogue: rotation-addressed transpose, write Vt (b,h,dh,s) ----
    asm volatile("s_waitcnt vmcnt(0)" ::: "memory");
    __syncthreads();   // all staging writes + reads done before aliasing SM
#pragma unroll
    for (int rb = 0; rb < 4; rb++)
#pragma unroll
      for (int cb = 0; cb < 4; cb++)
#pragma unroll
        for (int i = 0; i < 4; i++) {
          int row = wr * 64 + rb * 16 + lg * 4 + i;
          int col = wc * 64 + cb * 16 + l15;
          SM[row * 128 + ((col + row) & 127)] = f2bf(acc[rb][cb][i]);
        }
    __syncthreads();
    int b = m0 >> 11, s0 = m0 & (SQ - 1), h = n0 >> 7;
    int dh = t >> 1, sc = (t & 1) * 64;
    u16* dst = Ob + ((size_t)(b * NH + h) * HD + dh) * SQ + s0 + sc;
#pragma unroll
    for (int c8 = 0; c8 < 8; c8++) {
      u16x8 o;
#pragma unroll
      for (int e = 0; e < 8; e++) {
        int row = sc + c8 * 8 + e;
        o[e] = SM[row * 128 + ((dh + row) & 127)];
      }
      *(u16x8*)(dst + c8 * 8) = o;
    }
    return;
  }

#pragma unroll
  for (int rb = 0; rb < 4; rb++) {
#pragma unroll
    for (int cb = 0; cb < 4; cb++) {
#pragma unroll
      for (int i = 0; i < 4; i++) {
        float v = acc[rb][cb][i];
        int mm = m0 + wr * 64 + rb * 16 + lg * 4 + i;
        int nn = n0 + wc * 64 + cb * 16 + l15;
        if (MODE == 0) {
          int b = mm >> 11, s2 = mm & (SQ - 1), h = nn >> 7, dh = nn & (HD - 1);
          Ob[((size_t)(b * NH + h) * SQ + s2) * HD + dh] = f2bf(v);
        } else {
          Ofp[(size_t)mm * DIMD + nn] = v;
        }
      }
    }
  }
}

// ---------------- flash attention (swapped QK^T, 32 q-rows per wave) --------
// PROVEN r14/r16 version: KBLK=64, 80 KB LDS, 2 blocks/CU. Unchanged.
__global__ __launch_bounds__(256, 2) void attn_kernel(
    const u16* __restrict__ Q, const u16* __restrict__ K,
    const u16* __restrict__ Vt, u16* __restrict__ Aout) {
  __shared__ alignas(16) u16 Ksh[2][KBLK * HD];   // 2 x 16 KB
  __shared__ alignas(16) u16 Vsh[2][HD * KBLK];   // 2 x 16 KB
  __shared__ alignas(16) u16 Pl[4][32 * KBLK];    // 16 KB (per-wave, swizzled)
  int t = threadIdx.x;
  int wid = t >> 6, l = t & 63, l15 = l & 15, lg = l >> 4;
  int orig = blockIdx.x;
  int bid = (orig & 7) * 64 + (orig >> 3);
  int qb = bid & 15, bh = bid >> 4;
  int q0 = qb * QBLK + wid * 32;
  const u16* Qb = Q + ((size_t)bh * SQ + q0) * HD;
  const u16* Kb = K + (size_t)bh * SQ * HD;
  const u16* Vb = Vt + (size_t)bh * HD * SQ;

  s16x8 qf[2][4];
#pragma unroll
  for (int mq = 0; mq < 2; mq++)
#pragma unroll
    for (int ks = 0; ks < 4; ks++)
      qf[mq][ks] = *(const s16x8*)(Qb + (size_t)(mq * 16 + l15) * HD + ks * 32 + lg * 8);

  int od[4], kro[4], kco[4], vro[4], vco[4];
#pragma unroll
  for (int p2 = 0; p2 < 4; p2++) {
    int off = t * 16 + p2 * 4096;
    od[p2] = off;
    kro[p2] = off >> 8; kco[p2] = (off & 255) ^ ((kro[p2] & 7) << 4);
    vro[p2] = off >> 7; vco[p2] = (off & 127) ^ ((vro[p2] & 7) << 4);
  }

  auto stage = [&](int buf, int kb) {
    const u16* Kt = Kb + (size_t)kb * KBLK * HD;
    const u16* Vs = Vb + kb * KBLK;
#pragma unroll
    for (int p2 = 0; p2 < 4; p2++)
      gld16(Kt + (size_t)kro[p2] * HD + (kco[p2] >> 1), &Ksh[buf][od[p2] >> 1]);
#pragma unroll
    for (int p2 = 0; p2 < 4; p2++)
      gld16(Vs + (size_t)vro[p2] * SQ + (vco[p2] >> 1), &Vsh[buf][od[p2] >> 1]);
  };

  f32x4 acc[2][8];
#pragma unroll
  for (int mq = 0; mq < 2; mq++)
#pragma unroll
    for (int i = 0; i < 8; i++) acc[mq][i] = (f32x4){0.f, 0.f, 0.f, 0.f};
  float m[2] = {-3.0e38f, -3.0e38f}, lsum[2] = {0.f, 0.f};

  stage(0, 0);
  __syncthreads();

#pragma unroll 1
  for (int kb = 0; kb < SQ / KBLK; kb++) {
    int cur = kb & 1;
    if (kb + 1 < SQ / KBLK) stage(cur ^ 1, kb + 1);
    f32x4 sa[2][4];
#pragma unroll
    for (int mq = 0; mq < 2; mq++)
#pragma unroll
      for (int cb = 0; cb < 4; cb++) sa[mq][cb] = (f32x4){0.f, 0.f, 0.f, 0.f};
    __builtin_amdgcn_s_setprio(1);
#pragma unroll
    for (int ks = 0; ks < 4; ks++) {
#pragma unroll
      for (int cb = 0; cb < 4; cb++) {
        int r = cb * 16 + l15;
        int off = r * 256 + ((ks * 64 + lg * 16) ^ ((r & 7) << 4));
        s16x8 kf = *(const s16x8*)((const char*)&Ksh[cur][0] + off);
        sa[0][cb] = MFMA16(kf, qf[0][ks], sa[0][cb], 0, 0, 0);
        sa[1][cb] = MFMA16(kf, qf[1][ks], sa[1][cb], 0, 0, 0);
      }
    }
    __builtin_amdgcn_s_setprio(0);
    float rm[2];
#pragma unroll
    for (int mq = 0; mq < 2; mq++) {
      float r2 = sa[mq][0][0];
#pragma unroll
      for (int cb = 0; cb < 4; cb++)
#pragma unroll
        for (int i = 0; i < 4; i++) r2 = fmaxf(r2, sa[mq][cb][i]);
      r2 = fmaxf(r2, __shfl_xor(r2, 16));
      r2 = fmaxf(r2, __shfl_xor(r2, 32));
      rm[mq] = r2;
    }
    if (!__all(rm[0] <= m[0] + 8.0f && rm[1] <= m[1] + 8.0f)) {  // defer-max
#pragma unroll
      for (int mq = 0; mq < 2; mq++) {
        float mn = fmaxf(m[mq], rm[mq]);
        float al = __expf(m[mq] - mn);
        m[mq] = mn;
        float alq[4];
#pragma unroll
        for (int i = 0; i < 4; i++) alq[i] = __shfl(al, lg * 4 + i, 16);
#pragma unroll
        for (int c2 = 0; c2 < 8; c2++)
#pragma unroll
          for (int i = 0; i < 4; i++) acc[mq][c2][i] *= alq[i];
        lsum[mq] *= al;
      }
    }
#pragma unroll
    for (int mq = 0; mq < 2; mq++) {
      float ps = 0.f;
#pragma unroll
      for (int cb = 0; cb < 4; cb++)
#pragma unroll
        for (int i = 0; i < 4; i++) {
          sa[mq][cb][i] = __expf(sa[mq][cb][i] - m[mq]);
          ps += sa[mq][cb][i];
        }
      ps += __shfl_xor(ps, 16);
      ps += __shfl_xor(ps, 32);
      lsum[mq] += ps;
    }
#pragma unroll
    for (int mq = 0; mq < 2; mq++)
#pragma unroll
      for (int cb = 0; cb < 4; cb++) {
        u32 lo = (u32)f2bf(sa[mq][cb][0]) | ((u32)f2bf(sa[mq][cb][1]) << 16);
        u32 hi = (u32)f2bf(sa[mq][cb][2]) | ((u32)f2bf(sa[mq][cb][3]) << 16);
        int off = (mq * 16 + l15) * 128 + ((cb * 32 + lg * 8) ^ ((l15 & 7) << 4));
        *(uint2*)((char*)&Pl[wid][0] + off) = make_uint2(lo, hi);
      }
    s16x8 pf[2][2];
#pragma unroll
    for (int mq = 0; mq < 2; mq++)
#pragma unroll
      for (int k2 = 0; k2 < 2; k2++) {
        int off = (mq * 16 + l15) * 128 + ((k2 * 64 + lg * 16) ^ ((l15 & 7) << 4));
        pf[mq][k2] = *(const s16x8*)((const char*)&Pl[wid][0] + off);
      }
    __builtin_amdgcn_s_setprio(1);
#pragma unroll
    for (int c2 = 0; c2 < 8; c2++) {
#pragma unroll
      for (int k2 = 0; k2 < 2; k2++) {
        int r = c2 * 16 + l15;
        int off = r * 128 + ((k2 * 64 + lg * 16) ^ ((r & 7) << 4));
        s16x8 vf = *(const s16x8*)((const char*)&Vsh[cur][0] + off);
        acc[0][c2] = MFMA16(pf[0][k2], vf, acc[0][c2], 0, 0, 0);
        acc[1][c2] = MFMA16(pf[1][k2], vf, acc[1][c2], 0, 0, 0);
      }
    }
    __builtin_amdgcn_s_setprio(0);
    __syncthreads();
  }
  int b = bh >> 4, h = bh & (NH - 1);
#pragma unroll
  for (int mq = 0; mq < 2; mq++) {
    float rin = 1.0f / lsum[mq];
    float rq[4];
#pragma unroll
    for (int i = 0; i < 4; i++) rq[i] = __shfl(rin, lg * 4 + i, 16);
#pragma unroll
    for (int c2 = 0; c2 < 8; c2++) {
#pragma unroll
      for (int i = 0; i < 4; i++) {
        int q = q0 + mq * 16 + lg * 4 + i;
        int dh = c2 * 16 + l15;
        Aout[((size_t)b * SQ + q) * DIMD + h * HD + dh] = f2bf(acc[mq][c2][i] * rq[i]);
      }
    }
  }
}

extern "C" void kernel_launch(void* const* d_in, const int* in_sizes, int n_in,
                              void* d_out, int out_size, void* d_ws, size_t ws_size,
                              hipStream_t stream) {
  (void)in_sizes; (void)n_in; (void)out_size; (void)ws_size;
  const float* x    = (const float*)d_in[0];
  const float* wq   = (const float*)d_in[1];
  const float* wk   = (const float*)d_in[2];
  const float* wv   = (const float*)d_in[3];
  const float* wo   = (const float*)d_in[4];
  const float* cosT = (const float*)d_in[5];
  const float* sinT = (const float*)d_in[6];
  float* out = (float*)d_out;

  char* p = (char*)d_ws;
  const size_t SZ_MD = (size_t)MR * DIMD * 2;    // 16.78 MB
  const size_t SZ_W  = (size_t)DIMD * DIMD * 2;  // 8.39 MB
  u16* xb   = (u16*)p; p += SZ_MD;
  u16* wqb  = (u16*)p; p += SZ_W;   // wq,wk,wv,wo contiguous (cvt_all)
  u16* wkb  = (u16*)p; p += SZ_W;
  u16* wvb  = (u16*)p; p += SZ_W;
  u16* wob  = (u16*)p; p += SZ_W;
  u16* Qraw = (u16*)p; p += SZ_MD;
  u16* Kraw = (u16*)p; p += SZ_MD;
  u16* Qr   = (u16*)p; p += SZ_MD;
  u16* Kr   = (u16*)p; p += SZ_MD;
  u16* Vt   = (u16*)p; p += SZ_MD;
  u16* attnout = Qraw;  // Qraw dead after rope; reuse

  cvt_all<<<dim3(512, 5), 256, 0, stream>>>(x, wq, wk, wv, wo, xb, wqb);

  gemm_bt<0><<<dim3(512, 3), 256, 0, stream>>>(xb, wqb, wkb, wvb, Qraw, Kraw, Vt, nullptr);
  rope_kernel<<<dim3(16384, 2), 256, 0, stream>>>(Qraw, Kraw, Qr, Kr, cosT, sinT);
  attn_kernel<<<512, 256, 0, stream>>>(Qr, Kr, Vt, attnout);
  gemm_bt<1><<<dim3(512, 1), 256, 0, stream>>>(attnout, wob, nullptr, nullptr,
                                               nullptr, nullptr, nullptr, out);
}